// Round 1
// baseline (668.743 us; speedup 1.0000x reference)
//
#include <hip/hip_runtime.h>

#define N_NODES 100000
#define N_EDGES 1600000
#define D_IN 128
#define D 64
#define NBS ((N_NODES + 255) / 256)   // 391 scan blocks

// ---------------- CSR build ----------------

__global__ void k_hist(const int* __restrict__ dst, int* __restrict__ deg) {
    int e = blockIdx.x * 256 + threadIdx.x;
    if (e < N_EDGES) atomicAdd(&deg[dst[e]], 1);
}

__global__ void k_scan1(const int* __restrict__ deg, int* __restrict__ bsum) {
    __shared__ int s[256];
    int t = threadIdx.x;
    int i = blockIdx.x * 256 + t;
    s[t] = (i < N_NODES) ? deg[i] : 0;
    __syncthreads();
    for (int o = 128; o > 0; o >>= 1) {
        if (t < o) s[t] += s[t + o];
        __syncthreads();
    }
    if (t == 0) bsum[blockIdx.x] = s[0];
}

__global__ void k_scan2(const int* __restrict__ bsum, int* __restrict__ boff) {
    __shared__ int s[512];
    int t = threadIdx.x;
    int v = (t < NBS) ? bsum[t] : 0;
    s[t] = v;
    __syncthreads();
    for (int o = 1; o < 512; o <<= 1) {
        int x = (t >= o) ? s[t - o] : 0;
        __syncthreads();
        s[t] += x;
        __syncthreads();
    }
    if (t < NBS) boff[t] = s[t] - v;   // exclusive
}

// in-place: offs[] holds deg on entry, exclusive offsets on exit. cursor = copy.
__global__ void k_scan3(int* __restrict__ offs, const int* __restrict__ boff,
                        int* __restrict__ cursor) {
    __shared__ int s[256];
    int t = threadIdx.x;
    int i = blockIdx.x * 256 + t;
    int v = (i < N_NODES) ? offs[i] : 0;
    s[t] = v;
    __syncthreads();
    for (int o = 1; o < 256; o <<= 1) {
        int x = (t >= o) ? s[t - o] : 0;
        __syncthreads();
        s[t] += x;
        __syncthreads();
    }
    int off = boff[blockIdx.x] + s[t] - v;
    if (i < N_NODES) {
        offs[i] = off;
        cursor[i] = off;
        if (i == N_NODES - 1) offs[N_NODES] = off + v;
    }
}

__global__ void k_fill(const int* __restrict__ src, const int* __restrict__ dst,
                       int* __restrict__ cursor, int* __restrict__ csr) {
    int e = blockIdx.x * 256 + threadIdx.x;
    if (e < N_EDGES) {
        int d = dst[e];
        int p = atomicAdd(&cursor[d], 1);
        csr[p] = src[e];
    }
}

// ---------------- z = x @ w1a  (128 -> 64, no bias) ----------------
// block 256: 16 rows/pass, thread (r=t/16, c=t%16) computes cols 4c..4c+3 of row r.
__global__ __launch_bounds__(256) void k_gemm1(const float* __restrict__ x,
                                               const float* __restrict__ w,
                                               float* __restrict__ z) {
    __shared__ float ws[D_IN][D];        // 32 KB, flat matches w layout
    __shared__ float xs[16][D_IN + 1];   // +1 pad: scalar reads conflict-free
    int t = threadIdx.x;
    {
        const float4* w4 = (const float4*)w;
        float4* s4 = (float4*)&ws[0][0];
        for (int i = t; i < (D_IN * D) / 4; i += 256) s4[i] = w4[i];
    }
    int r = t >> 4, c = t & 15;
    __syncthreads();
    for (int base = blockIdx.x * 16; base < N_NODES; base += gridDim.x * 16) {
        // stage 16 rows (contiguous 8 KB), coalesced float4
        for (int i = t; i < 16 * (D_IN / 4); i += 256) {
            int row = i >> 5, k4 = i & 31;
            float4 v = ((const float4*)(x + (size_t)(base + row) * D_IN))[k4];
            xs[row][k4 * 4 + 0] = v.x; xs[row][k4 * 4 + 1] = v.y;
            xs[row][k4 * 4 + 2] = v.z; xs[row][k4 * 4 + 3] = v.w;
        }
        __syncthreads();
        float4 acc = {0.f, 0.f, 0.f, 0.f};
        for (int k = 0; k < D_IN; k++) {
            float xv = xs[r][k];
            float4 wv = *(const float4*)&ws[k][c * 4];
            acc.x += xv * wv.x; acc.y += xv * wv.y;
            acc.z += xv * wv.z; acc.w += xv * wv.w;
        }
        *(float4*)(z + (size_t)(base + r) * D + c * 4) = acc;
        __syncthreads();
    }
}

// ---------------- conv1 fused: agg(z) + b1a + relu, @w1b+b1b relu, @w2a -> u ----------------
__global__ __launch_bounds__(256) void k_conv1(const float* __restrict__ z,
                                               const int* __restrict__ offs,
                                               const int* __restrict__ csr,
                                               const float* __restrict__ b1a,
                                               const float* __restrict__ w1b,
                                               const float* __restrict__ b1b,
                                               const float* __restrict__ w2a,
                                               float* __restrict__ u) {
    __shared__ float w1s[D][D];          // 16 KB
    __shared__ float w2s[D][D];          // 16 KB
    __shared__ float h1s[16][D + 1];
    __shared__ float h2s[16][D + 1];
    int t = threadIdx.x;
    int r = t >> 4, c = t & 15;
    {
        const float4* a4 = (const float4*)w1b;
        float4* s4 = (float4*)&w1s[0][0];
        for (int i = t; i < (D * D) / 4; i += 256) s4[i] = a4[i];
        const float4* a5 = (const float4*)w2a;
        float4* s5 = (float4*)&w2s[0][0];
        for (int i = t; i < (D * D) / 4; i += 256) s5[i] = a5[i];
    }
    float4 vb1a = ((const float4*)b1a)[c];
    float4 vb1b = ((const float4*)b1b)[c];
    __syncthreads();

    for (int base = blockIdx.x * 16; base < N_NODES; base += gridDim.x * 16) {
        int node = base + r;   // N_NODES % 16 == 0, always valid
        // --- aggregate in 64-dim space ---
        float4 acc = *(const float4*)(z + (size_t)node * D + c * 4);
        acc.x += vb1a.x; acc.y += vb1a.y; acc.z += vb1a.z; acc.w += vb1a.w;
        int e0 = offs[node], e1 = offs[node + 1];
        for (int e = e0; e < e1; e++) {
            int s = csr[e];
            float4 v = *(const float4*)(z + (size_t)s * D + c * 4);
            acc.x += v.x; acc.y += v.y; acc.z += v.z; acc.w += v.w;
        }
        h1s[r][c * 4 + 0] = fmaxf(acc.x, 0.f);
        h1s[r][c * 4 + 1] = fmaxf(acc.y, 0.f);
        h1s[r][c * 4 + 2] = fmaxf(acc.z, 0.f);
        h1s[r][c * 4 + 3] = fmaxf(acc.w, 0.f);
        __syncthreads();
        // --- h2 = relu(h1 @ w1b + b1b) ---
        float4 a2 = vb1b;
        for (int k = 0; k < D; k++) {
            float hv = h1s[r][k];
            float4 wv = *(const float4*)&w1s[k][c * 4];
            a2.x += hv * wv.x; a2.y += hv * wv.y;
            a2.z += hv * wv.z; a2.w += hv * wv.w;
        }
        h2s[r][c * 4 + 0] = fmaxf(a2.x, 0.f);
        h2s[r][c * 4 + 1] = fmaxf(a2.y, 0.f);
        h2s[r][c * 4 + 2] = fmaxf(a2.z, 0.f);
        h2s[r][c * 4 + 3] = fmaxf(a2.w, 0.f);
        __syncthreads();
        // --- u = h2 @ w2a  (bias b2a applied in conv2 agg) ---
        float4 a3 = {0.f, 0.f, 0.f, 0.f};
        for (int k = 0; k < D; k++) {
            float hv = h2s[r][k];
            float4 wv = *(const float4*)&w2s[k][c * 4];
            a3.x += hv * wv.x; a3.y += hv * wv.y;
            a3.z += hv * wv.z; a3.w += hv * wv.w;
        }
        *(float4*)(u + (size_t)node * D + c * 4) = a3;
        __syncthreads();
    }
}

// ---------------- conv2 fused: agg(u) + b2a + relu -> column sum ----------------
__global__ __launch_bounds__(256) void k_conv2(const float* __restrict__ u,
                                               const int* __restrict__ offs,
                                               const int* __restrict__ csr,
                                               const float* __restrict__ b2a,
                                               float* __restrict__ colsum) {
    __shared__ float red[16][D + 1];
    int t = threadIdx.x;
    int r = t >> 4, c = t & 15;
    float4 vb = ((const float4*)b2a)[c];
    float4 cs = {0.f, 0.f, 0.f, 0.f};
    for (int base = blockIdx.x * 16; base < N_NODES; base += gridDim.x * 16) {
        int node = base + r;
        float4 acc = *(const float4*)(u + (size_t)node * D + c * 4);
        acc.x += vb.x; acc.y += vb.y; acc.z += vb.z; acc.w += vb.w;
        int e0 = offs[node], e1 = offs[node + 1];
        for (int e = e0; e < e1; e++) {
            int s = csr[e];
            float4 v = *(const float4*)(u + (size_t)s * D + c * 4);
            acc.x += v.x; acc.y += v.y; acc.z += v.z; acc.w += v.w;
        }
        cs.x += fmaxf(acc.x, 0.f); cs.y += fmaxf(acc.y, 0.f);
        cs.z += fmaxf(acc.z, 0.f); cs.w += fmaxf(acc.w, 0.f);
    }
    red[r][c * 4 + 0] = cs.x; red[r][c * 4 + 1] = cs.y;
    red[r][c * 4 + 2] = cs.z; red[r][c * 4 + 3] = cs.w;
    __syncthreads();
    if (r == 0) {
        float4 tot = {0.f, 0.f, 0.f, 0.f};
        for (int rr = 0; rr < 16; rr++) {
            tot.x += red[rr][c * 4 + 0]; tot.y += red[rr][c * 4 + 1];
            tot.z += red[rr][c * 4 + 2]; tot.w += red[rr][c * 4 + 3];
        }
        atomicAdd(&colsum[c * 4 + 0], tot.x);
        atomicAdd(&colsum[c * 4 + 1], tot.y);
        atomicAdd(&colsum[c * 4 + 2], tot.z);
        atomicAdd(&colsum[c * 4 + 3], tot.w);
    }
}

// ---------------- out = colsum @ w2b + N * b2b ----------------
__global__ void k_final(const float* __restrict__ colsum, const float* __restrict__ w2b,
                        const float* __restrict__ b2b, float* __restrict__ out) {
    int j = threadIdx.x;
    float acc = (float)N_NODES * b2b[j];
    for (int k = 0; k < D; k++) acc += colsum[k] * w2b[k * D + j];
    out[j] = acc;
}

// ---------------- launch ----------------

extern "C" void kernel_launch(void* const* d_in, const int* in_sizes, int n_in,
                              void* d_out, int out_size, void* d_ws, size_t ws_size,
                              hipStream_t stream) {
    const float* x   = (const float*)d_in[0];
    const int*   ei  = (const int*)d_in[1];
    const float* w1a = (const float*)d_in[2];
    const float* b1a = (const float*)d_in[3];
    const float* w1b = (const float*)d_in[4];
    const float* b1b = (const float*)d_in[5];
    const float* w2a = (const float*)d_in[6];
    const float* b2a = (const float*)d_in[7];
    const float* w2b = (const float*)d_in[8];
    const float* b2b = (const float*)d_in[9];
    float* out = (float*)d_out;

    const int* srcp = ei;
    const int* dstp = ei + N_EDGES;

    char* ws = (char*)d_ws;
    float* z      = (float*)(ws + 0);               // 25,600,000 B
    float* u      = (float*)(ws + 25600000);        // 25,600,000 B
    int*   offs   = (int*)(ws + 51200000);          // (N+1)*4 -> pad 400,128
    int*   cursor = (int*)(ws + 51600128);          // 400,000
    int*   csr    = (int*)(ws + 52000128);          // 6,400,000
    int*   bsum   = (int*)(ws + 58400128);          // 1,792
    int*   boff   = (int*)(ws + 58401920);          // 1,792
    float* colsum = (float*)(ws + 58403712);        // 256

    hipMemsetAsync(offs, 0, (N_NODES + 1) * sizeof(int), stream);
    hipMemsetAsync(colsum, 0, D * sizeof(float), stream);

    k_hist <<<(N_EDGES + 255) / 256, 256, 0, stream>>>(dstp, offs);
    k_scan1<<<NBS, 256, 0, stream>>>(offs, bsum);
    k_scan2<<<1, 512, 0, stream>>>(bsum, boff);
    k_scan3<<<NBS, 256, 0, stream>>>(offs, boff, cursor);
    k_fill <<<(N_EDGES + 255) / 256, 256, 0, stream>>>(srcp, dstp, cursor, csr);

    k_gemm1<<<2048, 256, 0, stream>>>(x, w1a, z);
    k_conv1<<<2048, 256, 0, stream>>>(z, offs, csr, b1a, w1b, b1b, w2a, u);
    k_conv2<<<2048, 256, 0, stream>>>(u, offs, csr, b2a, colsum);
    k_final<<<1, 64, 0, stream>>>(colsum, w2b, b2b, out);
}

// Round 2
// 575.638 us; speedup vs baseline: 1.1617x; 1.1617x over previous
//
#include <hip/hip_runtime.h>

#define N_NODES 100000
#define N_EDGES 1600000
#define D_IN 128
#define D 64
#define NBS ((N_NODES + 255) / 256)   // 391 scan blocks

__device__ __forceinline__ float bf2f(unsigned short u) {
    union { unsigned int i; float f; } q; q.i = ((unsigned int)u) << 16; return q.f;
}
__device__ __forceinline__ unsigned short f2bf(float f) {
    unsigned int u = __float_as_uint(f);
    unsigned int r = (u + 0x7FFFu + ((u >> 16) & 1u)) >> 16;   // RNE
    return (unsigned short)r;
}

// ---------------- CSR build ----------------

__global__ void k_hist(const int* __restrict__ dst, int* __restrict__ deg) {
    int e = blockIdx.x * 256 + threadIdx.x;
    if (e < N_EDGES) atomicAdd(&deg[dst[e]], 1);
}

__global__ void k_scan1(const int* __restrict__ deg, int* __restrict__ bsum) {
    __shared__ int s[256];
    int t = threadIdx.x;
    int i = blockIdx.x * 256 + t;
    s[t] = (i < N_NODES) ? deg[i] : 0;
    __syncthreads();
    for (int o = 128; o > 0; o >>= 1) {
        if (t < o) s[t] += s[t + o];
        __syncthreads();
    }
    if (t == 0) bsum[blockIdx.x] = s[0];
}

__global__ void k_scan2(const int* __restrict__ bsum, int* __restrict__ boff) {
    __shared__ int s[512];
    int t = threadIdx.x;
    int v = (t < NBS) ? bsum[t] : 0;
    s[t] = v;
    __syncthreads();
    for (int o = 1; o < 512; o <<= 1) {
        int x = (t >= o) ? s[t - o] : 0;
        __syncthreads();
        s[t] += x;
        __syncthreads();
    }
    if (t < NBS) boff[t] = s[t] - v;   // exclusive
}

// in-place: offs[] holds deg on entry, exclusive offsets on exit. cursor = copy.
__global__ void k_scan3(int* __restrict__ offs, const int* __restrict__ boff,
                        int* __restrict__ cursor) {
    __shared__ int s[256];
    int t = threadIdx.x;
    int i = blockIdx.x * 256 + t;
    int v = (i < N_NODES) ? offs[i] : 0;
    s[t] = v;
    __syncthreads();
    for (int o = 1; o < 256; o <<= 1) {
        int x = (t >= o) ? s[t - o] : 0;
        __syncthreads();
        s[t] += x;
        __syncthreads();
    }
    int off = boff[blockIdx.x] + s[t] - v;
    if (i < N_NODES) {
        offs[i] = off;
        cursor[i] = off;
        if (i == N_NODES - 1) offs[N_NODES] = off + v;
    }
}

__global__ void k_fill(const int* __restrict__ src, const int* __restrict__ dst,
                       int* __restrict__ cursor, int* __restrict__ csr) {
    int e = blockIdx.x * 256 + threadIdx.x;
    if (e < N_EDGES) {
        int d = dst[e];
        int p = atomicAdd(&cursor[d], 1);
        csr[p] = src[e];
    }
}

// ---------------- z = x @ w1a  (128 -> 64, no bias) ----------------
__global__ __launch_bounds__(256) void k_gemm1(const float* __restrict__ x,
                                               const float* __restrict__ w,
                                               float* __restrict__ z) {
    __shared__ float ws[D_IN][D];        // 32 KB
    __shared__ float xs[16][D_IN + 1];
    int t = threadIdx.x;
    {
        const float4* w4 = (const float4*)w;
        float4* s4 = (float4*)&ws[0][0];
        for (int i = t; i < (D_IN * D) / 4; i += 256) s4[i] = w4[i];
    }
    int r = t >> 4, c = t & 15;
    __syncthreads();
    for (int base = blockIdx.x * 16; base < N_NODES; base += gridDim.x * 16) {
        for (int i = t; i < 16 * (D_IN / 4); i += 256) {
            int row = i >> 5, k4 = i & 31;
            float4 v = ((const float4*)(x + (size_t)(base + row) * D_IN))[k4];
            xs[row][k4 * 4 + 0] = v.x; xs[row][k4 * 4 + 1] = v.y;
            xs[row][k4 * 4 + 2] = v.z; xs[row][k4 * 4 + 3] = v.w;
        }
        __syncthreads();
        float4 acc = {0.f, 0.f, 0.f, 0.f};
        for (int k = 0; k < D_IN; k++) {
            float xv = xs[r][k];
            float4 wv = *(const float4*)&ws[k][c * 4];
            acc.x += xv * wv.x; acc.y += xv * wv.y;
            acc.z += xv * wv.z; acc.w += xv * wv.w;
        }
        *(float4*)(z + (size_t)(base + r) * D + c * 4) = acc;
        __syncthreads();
    }
}

// ---------------- conv1 fused: agg(z)+b1a+relu, @w1b+b1b relu, @w2a -> u ----------------
// bf16 weights in LDS (16 KB total) -> ~24.7 KB/block -> 6 blocks/CU.
__global__ __launch_bounds__(256, 6) void k_conv1(const float* __restrict__ z,
                                                  const int* __restrict__ offs,
                                                  const int* __restrict__ csr,
                                                  const float* __restrict__ b1a,
                                                  const float* __restrict__ w1b,
                                                  const float* __restrict__ b1b,
                                                  const float* __restrict__ w2a,
                                                  float* __restrict__ u) {
    __shared__ unsigned short w1s[D][D];   // 8 KB bf16
    __shared__ unsigned short w2s[D][D];   // 8 KB bf16
    __shared__ float h1s[16][D + 1];
    __shared__ float h2s[16][D + 1];
    int t = threadIdx.x;
    int r = t >> 4, c = t & 15;
    {
        for (int i = t; i < (D * D) / 4; i += 256) {
            float4 a = ((const float4*)w1b)[i];
            ushort4 p; p.x = f2bf(a.x); p.y = f2bf(a.y); p.z = f2bf(a.z); p.w = f2bf(a.w);
            *(ushort4*)&(&w1s[0][0])[i * 4] = p;
            float4 b = ((const float4*)w2a)[i];
            ushort4 q; q.x = f2bf(b.x); q.y = f2bf(b.y); q.z = f2bf(b.z); q.w = f2bf(b.w);
            *(ushort4*)&(&w2s[0][0])[i * 4] = q;
        }
    }
    float4 vb1a = ((const float4*)b1a)[c];
    float4 vb1b = ((const float4*)b1b)[c];
    __syncthreads();

    const size_t c4 = (size_t)(c * 4);
    for (int base = blockIdx.x * 16; base < N_NODES; base += gridDim.x * 16) {
        int node = base + r;   // N_NODES % 16 == 0
        // --- aggregate in 64-dim space, 4-way unrolled for MLP ---
        float4 acc = *(const float4*)(z + (size_t)node * D + c4);
        acc.x += vb1a.x; acc.y += vb1a.y; acc.z += vb1a.z; acc.w += vb1a.w;
        int e0 = offs[node], e1 = offs[node + 1];
        int e = e0;
        for (; e + 4 <= e1; e += 4) {
            int s0 = csr[e + 0], s1 = csr[e + 1], s2 = csr[e + 2], s3 = csr[e + 3];
            float4 v0 = *(const float4*)(z + (size_t)s0 * D + c4);
            float4 v1 = *(const float4*)(z + (size_t)s1 * D + c4);
            float4 v2 = *(const float4*)(z + (size_t)s2 * D + c4);
            float4 v3 = *(const float4*)(z + (size_t)s3 * D + c4);
            acc.x += (v0.x + v1.x) + (v2.x + v3.x);
            acc.y += (v0.y + v1.y) + (v2.y + v3.y);
            acc.z += (v0.z + v1.z) + (v2.z + v3.z);
            acc.w += (v0.w + v1.w) + (v2.w + v3.w);
        }
        for (; e < e1; e++) {
            int s = csr[e];
            float4 v = *(const float4*)(z + (size_t)s * D + c4);
            acc.x += v.x; acc.y += v.y; acc.z += v.z; acc.w += v.w;
        }
        h1s[r][c * 4 + 0] = fmaxf(acc.x, 0.f);
        h1s[r][c * 4 + 1] = fmaxf(acc.y, 0.f);
        h1s[r][c * 4 + 2] = fmaxf(acc.z, 0.f);
        h1s[r][c * 4 + 3] = fmaxf(acc.w, 0.f);
        __syncthreads();
        // --- h2 = relu(h1 @ w1b + b1b) ---
        float4 a2 = vb1b;
        for (int k = 0; k < D; k++) {
            float hv = h1s[r][k];
            ushort4 wv = *(const ushort4*)&w1s[k][c * 4];
            a2.x += hv * bf2f(wv.x); a2.y += hv * bf2f(wv.y);
            a2.z += hv * bf2f(wv.z); a2.w += hv * bf2f(wv.w);
        }
        h2s[r][c * 4 + 0] = fmaxf(a2.x, 0.f);
        h2s[r][c * 4 + 1] = fmaxf(a2.y, 0.f);
        h2s[r][c * 4 + 2] = fmaxf(a2.z, 0.f);
        h2s[r][c * 4 + 3] = fmaxf(a2.w, 0.f);
        __syncthreads();
        // --- u = h2 @ w2a  (bias b2a applied in conv2 agg) ---
        float4 a3 = {0.f, 0.f, 0.f, 0.f};
        for (int k = 0; k < D; k++) {
            float hv = h2s[r][k];
            ushort4 wv = *(const ushort4*)&w2s[k][c * 4];
            a3.x += hv * bf2f(wv.x); a3.y += hv * bf2f(wv.y);
            a3.z += hv * bf2f(wv.z); a3.w += hv * bf2f(wv.w);
        }
        *(float4*)(u + (size_t)node * D + c4) = a3;
        __syncthreads();
    }
}

// ---------------- conv2 fused: agg(u) + b2a + relu -> column sum ----------------
__global__ __launch_bounds__(256) void k_conv2(const float* __restrict__ u,
                                               const int* __restrict__ offs,
                                               const int* __restrict__ csr,
                                               const float* __restrict__ b2a,
                                               float* __restrict__ colsum) {
    __shared__ float red[16][D + 1];
    int t = threadIdx.x;
    int r = t >> 4, c = t & 15;
    float4 vb = ((const float4*)b2a)[c];
    float4 cs = {0.f, 0.f, 0.f, 0.f};
    const size_t c4 = (size_t)(c * 4);
    for (int base = blockIdx.x * 16; base < N_NODES; base += gridDim.x * 16) {
        int node = base + r;
        float4 acc = *(const float4*)(u + (size_t)node * D + c4);
        acc.x += vb.x; acc.y += vb.y; acc.z += vb.z; acc.w += vb.w;
        int e0 = offs[node], e1 = offs[node + 1];
        int e = e0;
        for (; e + 4 <= e1; e += 4) {
            int s0 = csr[e + 0], s1 = csr[e + 1], s2 = csr[e + 2], s3 = csr[e + 3];
            float4 v0 = *(const float4*)(u + (size_t)s0 * D + c4);
            float4 v1 = *(const float4*)(u + (size_t)s1 * D + c4);
            float4 v2 = *(const float4*)(u + (size_t)s2 * D + c4);
            float4 v3 = *(const float4*)(u + (size_t)s3 * D + c4);
            acc.x += (v0.x + v1.x) + (v2.x + v3.x);
            acc.y += (v0.y + v1.y) + (v2.y + v3.y);
            acc.z += (v0.z + v1.z) + (v2.z + v3.z);
            acc.w += (v0.w + v1.w) + (v2.w + v3.w);
        }
        for (; e < e1; e++) {
            int s = csr[e];
            float4 v = *(const float4*)(u + (size_t)s * D + c4);
            acc.x += v.x; acc.y += v.y; acc.z += v.z; acc.w += v.w;
        }
        cs.x += fmaxf(acc.x, 0.f); cs.y += fmaxf(acc.y, 0.f);
        cs.z += fmaxf(acc.z, 0.f); cs.w += fmaxf(acc.w, 0.f);
    }
    red[r][c * 4 + 0] = cs.x; red[r][c * 4 + 1] = cs.y;
    red[r][c * 4 + 2] = cs.z; red[r][c * 4 + 3] = cs.w;
    __syncthreads();
    if (r == 0) {
        float4 tot = {0.f, 0.f, 0.f, 0.f};
        for (int rr = 0; rr < 16; rr++) {
            tot.x += red[rr][c * 4 + 0]; tot.y += red[rr][c * 4 + 1];
            tot.z += red[rr][c * 4 + 2]; tot.w += red[rr][c * 4 + 3];
        }
        atomicAdd(&colsum[c * 4 + 0], tot.x);
        atomicAdd(&colsum[c * 4 + 1], tot.y);
        atomicAdd(&colsum[c * 4 + 2], tot.z);
        atomicAdd(&colsum[c * 4 + 3], tot.w);
    }
}

// ---------------- out = colsum @ w2b + N * b2b ----------------
__global__ void k_final(const float* __restrict__ colsum, const float* __restrict__ w2b,
                        const float* __restrict__ b2b, float* __restrict__ out) {
    int j = threadIdx.x;
    float acc = (float)N_NODES * b2b[j];
    for (int k = 0; k < D; k++) acc += colsum[k] * w2b[k * D + j];
    out[j] = acc;
}

// ---------------- launch ----------------

extern "C" void kernel_launch(void* const* d_in, const int* in_sizes, int n_in,
                              void* d_out, int out_size, void* d_ws, size_t ws_size,
                              hipStream_t stream) {
    const float* x   = (const float*)d_in[0];
    const int*   ei  = (const int*)d_in[1];
    const float* w1a = (const float*)d_in[2];
    const float* b1a = (const float*)d_in[3];
    const float* w1b = (const float*)d_in[4];
    const float* b1b = (const float*)d_in[5];
    const float* w2a = (const float*)d_in[6];
    const float* b2a = (const float*)d_in[7];
    const float* w2b = (const float*)d_in[8];
    const float* b2b = (const float*)d_in[9];
    float* out = (float*)d_out;

    const int* srcp = ei;
    const int* dstp = ei + N_EDGES;

    char* ws = (char*)d_ws;
    float* z      = (float*)(ws + 0);               // 25,600,000 B
    float* u      = (float*)(ws + 25600000);        // 25,600,000 B
    int*   offs   = (int*)(ws + 51200000);          // (N+1)*4 -> pad 400,128
    int*   cursor = (int*)(ws + 51600128);          // 400,000
    int*   csr    = (int*)(ws + 52000128);          // 6,400,000
    int*   bsum   = (int*)(ws + 58400128);          // 1,792
    int*   boff   = (int*)(ws + 58401920);          // 1,792
    float* colsum = (float*)(ws + 58403712);        // 256

    hipMemsetAsync(offs, 0, (N_NODES + 1) * sizeof(int), stream);
    hipMemsetAsync(colsum, 0, D * sizeof(float), stream);

    k_hist <<<(N_EDGES + 255) / 256, 256, 0, stream>>>(dstp, offs);
    k_scan1<<<NBS, 256, 0, stream>>>(offs, bsum);
    k_scan2<<<1, 512, 0, stream>>>(bsum, boff);
    k_scan3<<<NBS, 256, 0, stream>>>(offs, boff, cursor);
    k_fill <<<(N_EDGES + 255) / 256, 256, 0, stream>>>(srcp, dstp, cursor, csr);

    k_gemm1<<<2048, 256, 0, stream>>>(x, w1a, z);
    k_conv1<<<2048, 256, 0, stream>>>(z, offs, csr, b1a, w1b, b1b, w2a, u);
    k_conv2<<<2048, 256, 0, stream>>>(u, offs, csr, b2a, colsum);
    k_final<<<1, 64, 0, stream>>>(colsum, w2b, b2b, out);
}

// Round 3
// 546.648 us; speedup vs baseline: 1.2234x; 1.0530x over previous
//
#include <hip/hip_runtime.h>

#define N_NODES 100000
#define N_EDGES 1600000
#define D_IN 128
#define D 64
#define NBS ((N_NODES + 255) / 256)   // 391 scan blocks

__device__ __forceinline__ float bf2f(unsigned short u) {
    union { unsigned int i; float f; } q; q.i = ((unsigned int)u) << 16; return q.f;
}
__device__ __forceinline__ unsigned short f2bf(float f) {
    unsigned int u = __float_as_uint(f);
    unsigned int r = (u + 0x7FFFu + ((u >> 16) & 1u)) >> 16;   // RNE
    return (unsigned short)r;
}
__device__ __forceinline__ void acc4(float4& a, ushort4 v) {
    a.x += bf2f(v.x); a.y += bf2f(v.y); a.z += bf2f(v.z); a.w += bf2f(v.w);
}

// ---------------- CSR build ----------------

__global__ void k_hist(const int* __restrict__ dst, int* __restrict__ deg) {
    int e = blockIdx.x * 256 + threadIdx.x;
    if (e < N_EDGES) atomicAdd(&deg[dst[e]], 1);
}

__global__ void k_scan1(const int* __restrict__ deg, int* __restrict__ bsum) {
    __shared__ int s[256];
    int t = threadIdx.x;
    int i = blockIdx.x * 256 + t;
    s[t] = (i < N_NODES) ? deg[i] : 0;
    __syncthreads();
    for (int o = 128; o > 0; o >>= 1) {
        if (t < o) s[t] += s[t + o];
        __syncthreads();
    }
    if (t == 0) bsum[blockIdx.x] = s[0];
}

__global__ void k_scan2(const int* __restrict__ bsum, int* __restrict__ boff) {
    __shared__ int s[512];
    int t = threadIdx.x;
    int v = (t < NBS) ? bsum[t] : 0;
    s[t] = v;
    __syncthreads();
    for (int o = 1; o < 512; o <<= 1) {
        int x = (t >= o) ? s[t - o] : 0;
        __syncthreads();
        s[t] += x;
        __syncthreads();
    }
    if (t < NBS) boff[t] = s[t] - v;   // exclusive
}

// in-place: offs[] holds deg on entry, exclusive offsets on exit. cursor = copy.
__global__ void k_scan3(int* __restrict__ offs, const int* __restrict__ boff,
                        int* __restrict__ cursor) {
    __shared__ int s[256];
    int t = threadIdx.x;
    int i = blockIdx.x * 256 + t;
    int v = (i < N_NODES) ? offs[i] : 0;
    s[t] = v;
    __syncthreads();
    for (int o = 1; o < 256; o <<= 1) {
        int x = (t >= o) ? s[t - o] : 0;
        __syncthreads();
        s[t] += x;
        __syncthreads();
    }
    int off = boff[blockIdx.x] + s[t] - v;
    if (i < N_NODES) {
        offs[i] = off;
        cursor[i] = off;
        if (i == N_NODES - 1) offs[N_NODES] = off + v;
    }
}

__global__ void k_fill(const int* __restrict__ src, const int* __restrict__ dst,
                       int* __restrict__ cursor, int* __restrict__ csr) {
    int e = blockIdx.x * 256 + threadIdx.x;
    if (e < N_EDGES) {
        int d = dst[e];
        int p = atomicAdd(&cursor[d], 1);
        csr[p] = src[e];
    }
}

// ---------------- z = x @ w1a  (128 -> 64, no bias), z stored bf16 ----------------
__global__ __launch_bounds__(256) void k_gemm1(const float* __restrict__ x,
                                               const float* __restrict__ w,
                                               unsigned short* __restrict__ z) {
    __shared__ float ws[D_IN][D];        // 32 KB
    __shared__ float xs[16][D_IN + 1];
    int t = threadIdx.x;
    {
        const float4* w4 = (const float4*)w;
        float4* s4 = (float4*)&ws[0][0];
        for (int i = t; i < (D_IN * D) / 4; i += 256) s4[i] = w4[i];
    }
    int r = t >> 4, c = t & 15;
    __syncthreads();
    for (int base = blockIdx.x * 16; base < N_NODES; base += gridDim.x * 16) {
        for (int i = t; i < 16 * (D_IN / 4); i += 256) {
            int row = i >> 5, k4 = i & 31;
            float4 v = ((const float4*)(x + (size_t)(base + row) * D_IN))[k4];
            xs[row][k4 * 4 + 0] = v.x; xs[row][k4 * 4 + 1] = v.y;
            xs[row][k4 * 4 + 2] = v.z; xs[row][k4 * 4 + 3] = v.w;
        }
        __syncthreads();
        float4 acc = {0.f, 0.f, 0.f, 0.f};
        for (int k = 0; k < D_IN; k++) {
            float xv = xs[r][k];
            float4 wv = *(const float4*)&ws[k][c * 4];
            acc.x += xv * wv.x; acc.y += xv * wv.y;
            acc.z += xv * wv.z; acc.w += xv * wv.w;
        }
        ushort4 p;
        p.x = f2bf(acc.x); p.y = f2bf(acc.y); p.z = f2bf(acc.z); p.w = f2bf(acc.w);
        *(ushort4*)(z + (size_t)(base + r) * D + c * 4) = p;
        __syncthreads();
    }
}

// ---------------- conv1 fused: agg(z)+b1a+relu, @w1b+b1b relu, @w2a -> u (bf16) ----------------
__global__ __launch_bounds__(256, 6) void k_conv1(const unsigned short* __restrict__ z,
                                                  const int* __restrict__ offs,
                                                  const int* __restrict__ csr,
                                                  const float* __restrict__ b1a,
                                                  const float* __restrict__ w1b,
                                                  const float* __restrict__ b1b,
                                                  const float* __restrict__ w2a,
                                                  unsigned short* __restrict__ u) {
    __shared__ unsigned short w1s[D][D];   // 8 KB bf16
    __shared__ unsigned short w2s[D][D];   // 8 KB bf16
    __shared__ float h1s[16][D + 1];
    __shared__ float h2s[16][D + 1];
    int t = threadIdx.x;
    int r = t >> 4, c = t & 15;
    {
        for (int i = t; i < (D * D) / 4; i += 256) {
            float4 a = ((const float4*)w1b)[i];
            ushort4 p; p.x = f2bf(a.x); p.y = f2bf(a.y); p.z = f2bf(a.z); p.w = f2bf(a.w);
            *(ushort4*)&(&w1s[0][0])[i * 4] = p;
            float4 b = ((const float4*)w2a)[i];
            ushort4 q; q.x = f2bf(b.x); q.y = f2bf(b.y); q.z = f2bf(b.z); q.w = f2bf(b.w);
            *(ushort4*)&(&w2s[0][0])[i * 4] = q;
        }
    }
    float4 vb1a = ((const float4*)b1a)[c];
    float4 vb1b = ((const float4*)b1b)[c];
    __syncthreads();

    const size_t c4 = (size_t)(c * 4);
    for (int base = blockIdx.x * 16; base < N_NODES; base += gridDim.x * 16) {
        int node = base + r;   // N_NODES % 16 == 0
        // --- aggregate in 64-dim bf16 space, 8-deep load pipeline ---
        float4 acc = {vb1a.x, vb1a.y, vb1a.z, vb1a.w};
        acc4(acc, *(const ushort4*)(z + (size_t)node * D + c4));
        int e0 = offs[node], e1 = offs[node + 1];
        int e = e0;
        for (; e + 8 <= e1; e += 8) {
            int s0 = csr[e + 0], s1 = csr[e + 1], s2 = csr[e + 2], s3 = csr[e + 3];
            int s4 = csr[e + 4], s5 = csr[e + 5], s6 = csr[e + 6], s7 = csr[e + 7];
            ushort4 v0 = *(const ushort4*)(z + (size_t)s0 * D + c4);
            ushort4 v1 = *(const ushort4*)(z + (size_t)s1 * D + c4);
            ushort4 v2 = *(const ushort4*)(z + (size_t)s2 * D + c4);
            ushort4 v3 = *(const ushort4*)(z + (size_t)s3 * D + c4);
            ushort4 v4 = *(const ushort4*)(z + (size_t)s4 * D + c4);
            ushort4 v5 = *(const ushort4*)(z + (size_t)s5 * D + c4);
            ushort4 v6 = *(const ushort4*)(z + (size_t)s6 * D + c4);
            ushort4 v7 = *(const ushort4*)(z + (size_t)s7 * D + c4);
            acc4(acc, v0); acc4(acc, v1); acc4(acc, v2); acc4(acc, v3);
            acc4(acc, v4); acc4(acc, v5); acc4(acc, v6); acc4(acc, v7);
        }
        for (; e < e1; e++) {
            int s = csr[e];
            acc4(acc, *(const ushort4*)(z + (size_t)s * D + c4));
        }
        h1s[r][c * 4 + 0] = fmaxf(acc.x, 0.f);
        h1s[r][c * 4 + 1] = fmaxf(acc.y, 0.f);
        h1s[r][c * 4 + 2] = fmaxf(acc.z, 0.f);
        h1s[r][c * 4 + 3] = fmaxf(acc.w, 0.f);
        __syncthreads();
        // --- h2 = relu(h1 @ w1b + b1b) ---
        float4 a2 = vb1b;
        for (int k = 0; k < D; k++) {
            float hv = h1s[r][k];
            ushort4 wv = *(const ushort4*)&w1s[k][c * 4];
            a2.x += hv * bf2f(wv.x); a2.y += hv * bf2f(wv.y);
            a2.z += hv * bf2f(wv.z); a2.w += hv * bf2f(wv.w);
        }
        h2s[r][c * 4 + 0] = fmaxf(a2.x, 0.f);
        h2s[r][c * 4 + 1] = fmaxf(a2.y, 0.f);
        h2s[r][c * 4 + 2] = fmaxf(a2.z, 0.f);
        h2s[r][c * 4 + 3] = fmaxf(a2.w, 0.f);
        __syncthreads();
        // --- u = h2 @ w2a  (bias b2a applied in conv2 agg), u stored bf16 ---
        float4 a3 = {0.f, 0.f, 0.f, 0.f};
        for (int k = 0; k < D; k++) {
            float hv = h2s[r][k];
            ushort4 wv = *(const ushort4*)&w2s[k][c * 4];
            a3.x += hv * bf2f(wv.x); a3.y += hv * bf2f(wv.y);
            a3.z += hv * bf2f(wv.z); a3.w += hv * bf2f(wv.w);
        }
        ushort4 p;
        p.x = f2bf(a3.x); p.y = f2bf(a3.y); p.z = f2bf(a3.z); p.w = f2bf(a3.w);
        *(ushort4*)(u + (size_t)node * D + c4) = p;
        __syncthreads();
    }
}

// ---------------- conv2 fused: agg(u) + b2a + relu -> column sum ----------------
__global__ __launch_bounds__(256) void k_conv2(const unsigned short* __restrict__ u,
                                               const int* __restrict__ offs,
                                               const int* __restrict__ csr,
                                               const float* __restrict__ b2a,
                                               float* __restrict__ colsum) {
    __shared__ float red[16][D + 1];
    int t = threadIdx.x;
    int r = t >> 4, c = t & 15;
    float4 vb = ((const float4*)b2a)[c];
    float4 cs = {0.f, 0.f, 0.f, 0.f};
    const size_t c4 = (size_t)(c * 4);
    for (int base = blockIdx.x * 16; base < N_NODES; base += gridDim.x * 16) {
        int node = base + r;
        float4 acc = {vb.x, vb.y, vb.z, vb.w};
        acc4(acc, *(const ushort4*)(u + (size_t)node * D + c4));
        int e0 = offs[node], e1 = offs[node + 1];
        int e = e0;
        for (; e + 8 <= e1; e += 8) {
            int s0 = csr[e + 0], s1 = csr[e + 1], s2 = csr[e + 2], s3 = csr[e + 3];
            int s4 = csr[e + 4], s5 = csr[e + 5], s6 = csr[e + 6], s7 = csr[e + 7];
            ushort4 v0 = *(const ushort4*)(u + (size_t)s0 * D + c4);
            ushort4 v1 = *(const ushort4*)(u + (size_t)s1 * D + c4);
            ushort4 v2 = *(const ushort4*)(u + (size_t)s2 * D + c4);
            ushort4 v3 = *(const ushort4*)(u + (size_t)s3 * D + c4);
            ushort4 v4 = *(const ushort4*)(u + (size_t)s4 * D + c4);
            ushort4 v5 = *(const ushort4*)(u + (size_t)s5 * D + c4);
            ushort4 v6 = *(const ushort4*)(u + (size_t)s6 * D + c4);
            ushort4 v7 = *(const ushort4*)(u + (size_t)s7 * D + c4);
            acc4(acc, v0); acc4(acc, v1); acc4(acc, v2); acc4(acc, v3);
            acc4(acc, v4); acc4(acc, v5); acc4(acc, v6); acc4(acc, v7);
        }
        for (; e < e1; e++) {
            int s = csr[e];
            acc4(acc, *(const ushort4*)(u + (size_t)s * D + c4));
        }
        cs.x += fmaxf(acc.x, 0.f); cs.y += fmaxf(acc.y, 0.f);
        cs.z += fmaxf(acc.z, 0.f); cs.w += fmaxf(acc.w, 0.f);
    }
    red[r][c * 4 + 0] = cs.x; red[r][c * 4 + 1] = cs.y;
    red[r][c * 4 + 2] = cs.z; red[r][c * 4 + 3] = cs.w;
    __syncthreads();
    if (r == 0) {
        float4 tot = {0.f, 0.f, 0.f, 0.f};
        for (int rr = 0; rr < 16; rr++) {
            tot.x += red[rr][c * 4 + 0]; tot.y += red[rr][c * 4 + 1];
            tot.z += red[rr][c * 4 + 2]; tot.w += red[rr][c * 4 + 3];
        }
        atomicAdd(&colsum[c * 4 + 0], tot.x);
        atomicAdd(&colsum[c * 4 + 1], tot.y);
        atomicAdd(&colsum[c * 4 + 2], tot.z);
        atomicAdd(&colsum[c * 4 + 3], tot.w);
    }
}

// ---------------- out = colsum @ w2b + N * b2b ----------------
__global__ void k_final(const float* __restrict__ colsum, const float* __restrict__ w2b,
                        const float* __restrict__ b2b, float* __restrict__ out) {
    int j = threadIdx.x;
    float acc = (float)N_NODES * b2b[j];
    for (int k = 0; k < D; k++) acc += colsum[k] * w2b[k * D + j];
    out[j] = acc;
}

// ---------------- launch ----------------

extern "C" void kernel_launch(void* const* d_in, const int* in_sizes, int n_in,
                              void* d_out, int out_size, void* d_ws, size_t ws_size,
                              hipStream_t stream) {
    const float* x   = (const float*)d_in[0];
    const int*   ei  = (const int*)d_in[1];
    const float* w1a = (const float*)d_in[2];
    const float* b1a = (const float*)d_in[3];
    const float* w1b = (const float*)d_in[4];
    const float* b1b = (const float*)d_in[5];
    const float* w2a = (const float*)d_in[6];
    const float* b2a = (const float*)d_in[7];
    const float* w2b = (const float*)d_in[8];
    const float* b2b = (const float*)d_in[9];
    float* out = (float*)d_out;

    const int* srcp = ei;
    const int* dstp = ei + N_EDGES;

    char* ws = (char*)d_ws;
    unsigned short* z = (unsigned short*)(ws + 0);        // 12,800,000 B
    unsigned short* u = (unsigned short*)(ws + 12800000); // 12,800,000 B
    int*   offs   = (int*)(ws + 25600000);          // (N+1)*4 -> pad 400,128
    int*   cursor = (int*)(ws + 26000128);          // 400,000
    int*   csr    = (int*)(ws + 26400128);          // 6,400,000
    int*   bsum   = (int*)(ws + 32800128);          // 1,792
    int*   boff   = (int*)(ws + 32801920);          // 1,792
    float* colsum = (float*)(ws + 32803712);        // 256

    hipMemsetAsync(offs, 0, (N_NODES + 1) * sizeof(int), stream);
    hipMemsetAsync(colsum, 0, D * sizeof(float), stream);

    k_hist <<<(N_EDGES + 255) / 256, 256, 0, stream>>>(dstp, offs);
    k_scan1<<<NBS, 256, 0, stream>>>(offs, bsum);
    k_scan2<<<1, 512, 0, stream>>>(bsum, boff);
    k_scan3<<<NBS, 256, 0, stream>>>(offs, boff, cursor);
    k_fill <<<(N_EDGES + 255) / 256, 256, 0, stream>>>(srcp, dstp, cursor, csr);

    k_gemm1<<<2048, 256, 0, stream>>>(x, w1a, z);
    k_conv1<<<2048, 256, 0, stream>>>(z, offs, csr, b1a, w1b, b1b, w2a, u);
    k_conv2<<<2048, 256, 0, stream>>>(u, offs, csr, b2a, colsum);
    k_final<<<1, 64, 0, stream>>>(colsum, w2b, b2b, out);
}